// Round 1
// baseline (107.913 us; speedup 1.0000x reference)
//
#include <hip/hip_runtime.h>
#include <stdint.h>

#define B_ROWS 4096
#define D 256
#define NTOT (2 * B_ROWS)        // 8192 rows
#define TEMP_INV 2.0f            // 1 / 0.5

#define NSPLIT 16
#define BM 128                                // rows per gemm block
#define COLS_PER_BLOCK (NTOT / NSPLIT)        // 512
#define JT_COUNT (COLS_PER_BLOCK / 64)        // 8

typedef __attribute__((ext_vector_type(8))) short bf16x8;
typedef __attribute__((ext_vector_type(4))) float f32x4;
typedef __attribute__((ext_vector_type(4))) unsigned short us4;

typedef const __attribute__((address_space(1))) char gch;
typedef __attribute__((address_space(3))) char lch;

static __device__ __forceinline__ unsigned short f2bf(float f) {
  union { float f; unsigned u; } v; v.f = f;
  unsigned r = v.u + 0x7FFFu + ((v.u >> 16) & 1u);   // RNE
  return (unsigned short)(r >> 16);
}
static __device__ __forceinline__ float bf2f(unsigned short u) {
  union { unsigned u; float f; } v; v.u = ((unsigned)u) << 16;
  return v.f;
}

// ---------------- kernel 1: normalize rows, emit bf16 zn ----------------
__global__ __launch_bounds__(256) void k_prep(const float* __restrict__ xi,
                                              const float* __restrict__ xj,
                                              unsigned short* __restrict__ zn) {
  int row = blockIdx.x * 4 + (threadIdx.x >> 6);
  int lane = threadIdx.x & 63;
  const float* src = (row < B_ROWS) ? (xi + (size_t)row * D)
                                    : (xj + (size_t)(row - B_ROWS) * D);
  float4 v = ((const float4*)src)[lane];               // 64 lanes x 4 = 256
  float ss = v.x * v.x + v.y * v.y + v.z * v.z + v.w * v.w;
  #pragma unroll
  for (int m = 1; m < 64; m <<= 1) ss += __shfl_xor(ss, m, 64);
  float inv = 1.0f / fmaxf(sqrtf(ss), 1e-8f);
  us4 o;
  o.x = f2bf(v.x * inv); o.y = f2bf(v.y * inv);
  o.z = f2bf(v.z * inv); o.w = f2bf(v.w * inv);
  *(us4*)(zn + (size_t)row * D + lane * 4) = o;
}

// ---------------- kernel 2: positive-pair similarities ----------------
__global__ __launch_bounds__(256) void k_pos(const unsigned short* __restrict__ zn,
                                             float* __restrict__ pos) {
  int i = blockIdx.x * 4 + (threadIdx.x >> 6);
  int lane = threadIdx.x & 63;
  int j = (i < B_ROWS) ? (i + B_ROWS) : (i - B_ROWS);
  us4 a = *(const us4*)(zn + (size_t)i * D + lane * 4);
  us4 b = *(const us4*)(zn + (size_t)j * D + lane * 4);
  float d = bf2f(a.x) * bf2f(b.x) + bf2f(a.y) * bf2f(b.y) +
            bf2f(a.z) * bf2f(b.z) + bf2f(a.w) * bf2f(b.w);
  #pragma unroll
  for (int m = 1; m < 64; m <<= 1) d += __shfl_xor(d, m, 64);
  if (lane == 0) pos[i] = d;
}

// ---------------- kernel 3: fused sim-GEMM + exp row-sum ----------------
// grid = (NTOT/BM) * NSPLIT = 64*16 = 1024 blocks, 256 threads (4 waves).
// Wave w owns rows [rb + 32w, rb + 32w + 32) as two 16-row MFMA A-tiles.
// Columns tiled 64 at a time into LDS ([64][256] bf16 = 32 KB), staged with
// global_load_lds (linear dest) + pre-swizzled global source; reads apply the
// same XOR ((row&7)<<4) -> conflict-free ds_read_b128 (rule #21 / G4).
__global__ __launch_bounds__(256) void k_gemm(const unsigned short* __restrict__ zn,
                                              float* __restrict__ rowsum) {
  __shared__ char lds[64 * 512];
  int rb = (int)(blockIdx.x / NSPLIT) * BM;
  int cb = (int)(blockIdx.x % NSPLIT) * COLS_PER_BLOCK;
  int w = threadIdx.x >> 6;
  int lane = threadIdx.x & 63;
  int hi = lane >> 4, lo = lane & 15;

  const char* znb = (const char*)zn;

  // A fragments (held in registers): lane -> row = (l&15), k = 32f + (l>>4)*8
  bf16x8 a0[8], a1[8];
  int r0 = rb + w * 32 + lo;
  #pragma unroll
  for (int f = 0; f < 8; f++) {
    a0[f] = *(const bf16x8*)(znb + (size_t)r0 * 512 + f * 64 + hi * 16);
    a1[f] = *(const bf16x8*)(znb + (size_t)(r0 + 16) * 512 + f * 64 + hi * 16);
  }

  float rs[2][4] = {{0.f, 0.f, 0.f, 0.f}, {0.f, 0.f, 0.f, 0.f}};

  for (int jt = 0; jt < JT_COUNT; jt++) {
    int colbase = cb + jt * 64;
    __syncthreads();   // all waves done reading LDS before overwrite
    #pragma unroll
    for (int it = 0; it < 8; it++) {
      int local = w * 8192 + it * 1024 + lane * 16;         // linear LDS offset
      int src = local ^ (((local >> 9) & 7) << 4);          // inverse-swizzled source
      __builtin_amdgcn_global_load_lds(
          (gch*)(znb + (size_t)colbase * 512 + src),
          (lch*)(lds + w * 8192 + it * 1024), 16, 0, 0);
    }
    asm volatile("s_waitcnt vmcnt(0)");
    __syncthreads();

    #pragma unroll
    for (int nt = 0; nt < 4; nt++) {
      int ldrow = nt * 16 + lo;
      int sw = (ldrow & 7) << 4;
      bf16x8 b[8];
      #pragma unroll
      for (int f = 0; f < 8; f++) {
        int off = ldrow * 512 + f * 64 + hi * 16;
        b[f] = *(const bf16x8*)(lds + (off ^ sw));
      }
      f32x4 acc0 = {0.f, 0.f, 0.f, 0.f}, acc1 = {0.f, 0.f, 0.f, 0.f};
      #pragma unroll
      for (int f = 0; f < 8; f++) {
        acc0 = __builtin_amdgcn_mfma_f32_16x16x32_bf16(a0[f], b[f], acc0, 0, 0, 0);
        acc1 = __builtin_amdgcn_mfma_f32_16x16x32_bf16(a1[f], b[f], acc1, 0, 0, 0);
      }
      #pragma unroll
      for (int r = 0; r < 4; r++) {
        rs[0][r] += __expf(TEMP_INV * acc0[r]);
        rs[1][r] += __expf(TEMP_INV * acc1[r]);
      }
    }
  }

  // reduce partial row-sums across the 16 lanes of each row-group
  #pragma unroll
  for (int m = 1; m < 16; m <<= 1) {
    #pragma unroll
    for (int t = 0; t < 2; t++)
      #pragma unroll
      for (int r = 0; r < 4; r++)
        rs[t][r] += __shfl_xor(rs[t][r], m, 64);
  }
  if (lo == 0) {
    #pragma unroll
    for (int t = 0; t < 2; t++)
      #pragma unroll
      for (int r = 0; r < 4; r++)
        atomicAdd(&rowsum[rb + w * 32 + t * 16 + hi * 4 + r], rs[t][r]);
  }
}

// ---------------- kernel 4: final loss reduction ----------------
__global__ __launch_bounds__(256) void k_final(const float* __restrict__ rowsum,
                                               const float* __restrict__ pos,
                                               float* __restrict__ out) {
  int i = blockIdx.x * 256 + threadIdx.x;
  float denom = rowsum[i] - 7.3890560989306495f;   // subtract exp(2*sim_ii), sim_ii=1
  float t = __logf(denom) - TEMP_INV * pos[i];
  #pragma unroll
  for (int m = 1; m < 64; m <<= 1) t += __shfl_xor(t, m, 64);
  __shared__ float wsum[4];
  int w = threadIdx.x >> 6, lane = threadIdx.x & 63;
  if (lane == 0) wsum[w] = t;
  __syncthreads();
  if (threadIdx.x == 0) {
    float s = wsum[0] + wsum[1] + wsum[2] + wsum[3];
    atomicAdd(out, s * (1.0f / NTOT));
  }
}

extern "C" void kernel_launch(void* const* d_in, const int* in_sizes, int n_in,
                              void* d_out, int out_size, void* d_ws, size_t ws_size,
                              hipStream_t stream) {
  const float* xi = (const float*)d_in[0];
  const float* xj = (const float*)d_in[1];

  unsigned short* zn = (unsigned short*)d_ws;                       // 4 MB bf16 zn
  char* base = (char*)d_ws + (size_t)NTOT * D * 2;
  float* rowsum = (float*)base;                                     // 32 KB
  float* pos = (float*)(base + (size_t)NTOT * 4);                   // 32 KB

  hipMemsetAsync(rowsum, 0, NTOT * sizeof(float), stream);
  hipMemsetAsync(d_out, 0, out_size * sizeof(float), stream);

  k_prep<<<NTOT / 4, 256, 0, stream>>>(xi, xj, zn);
  k_pos<<<NTOT / 4, 256, 0, stream>>>(zn, pos);
  k_gemm<<<(NTOT / BM) * NSPLIT, 256, 0, stream>>>(zn, rowsum);
  k_final<<<NTOT / 256, 256, 0, stream>>>(rowsum, pos, (float*)d_out);
}

// Round 2
// 100.313 us; speedup vs baseline: 1.0758x; 1.0758x over previous
//
#include <hip/hip_runtime.h>
#include <stdint.h>

#define B_ROWS 4096
#define D 256
#define NTOT (2 * B_ROWS)        // 8192 rows
#define NSPLIT 16
#define BM 256                   // rows per gemm block
#define COLS_PER_BLOCK (NTOT / NSPLIT)        // 512
#define JT_COUNT (COLS_PER_BLOCK / 64)        // 8
#define C_SCALE 2.8853900817779268f           // (1/T)*log2(e) = 2*log2(e)

typedef __attribute__((ext_vector_type(8))) short bf16x8;
typedef __attribute__((ext_vector_type(4))) float f32x4;
typedef __attribute__((ext_vector_type(4))) unsigned short us4;

typedef const __attribute__((address_space(1))) char gch;
typedef __attribute__((address_space(3))) char lch;

static __device__ __forceinline__ unsigned short f2bf(float f) {
  union { float f; unsigned u; } v; v.f = f;
  unsigned r = v.u + 0x7FFFu + ((v.u >> 16) & 1u);   // RNE
  return (unsigned short)(r >> 16);
}

// ---- kernel 1: normalize rows -> bf16 zn (and 2*log2e-scaled zns), pos ----
// One wave per pair (row i of x_i, row i of x_j). Also zeroes d_out.
__global__ __launch_bounds__(256) void k_prep(const float* __restrict__ xi,
                                              const float* __restrict__ xj,
                                              unsigned short* __restrict__ zn,
                                              unsigned short* __restrict__ zns,
                                              float* __restrict__ pos,
                                              float* __restrict__ out) {
  if (blockIdx.x == 0 && threadIdx.x == 0) out[0] = 0.0f;
  int p = blockIdx.x * 4 + (threadIdx.x >> 6);
  int lane = threadIdx.x & 63;
  float4 a = ((const float4*)(xi + (size_t)p * D))[lane];
  float4 b = ((const float4*)(xj + (size_t)p * D))[lane];
  float sa = a.x * a.x + a.y * a.y + a.z * a.z + a.w * a.w;
  float sb = b.x * b.x + b.y * b.y + b.z * b.z + b.w * b.w;
  float ab = a.x * b.x + a.y * b.y + a.z * b.z + a.w * b.w;
  #pragma unroll
  for (int m = 1; m < 64; m <<= 1) {
    sa += __shfl_xor(sa, m, 64);
    sb += __shfl_xor(sb, m, 64);
    ab += __shfl_xor(ab, m, 64);
  }
  float ia = 1.0f / fmaxf(sqrtf(sa), 1e-8f);
  float ib = 1.0f / fmaxf(sqrtf(sb), 1e-8f);
  float na[4] = {a.x * ia, a.y * ia, a.z * ia, a.w * ia};
  float nb[4] = {b.x * ib, b.y * ib, b.z * ib, b.w * ib};
  us4 oa, ob, sa4, sb4;
  oa.x = f2bf(na[0]); oa.y = f2bf(na[1]); oa.z = f2bf(na[2]); oa.w = f2bf(na[3]);
  ob.x = f2bf(nb[0]); ob.y = f2bf(nb[1]); ob.z = f2bf(nb[2]); ob.w = f2bf(nb[3]);
  sa4.x = f2bf(na[0] * C_SCALE); sa4.y = f2bf(na[1] * C_SCALE);
  sa4.z = f2bf(na[2] * C_SCALE); sa4.w = f2bf(na[3] * C_SCALE);
  sb4.x = f2bf(nb[0] * C_SCALE); sb4.y = f2bf(nb[1] * C_SCALE);
  sb4.z = f2bf(nb[2] * C_SCALE); sb4.w = f2bf(nb[3] * C_SCALE);
  *(us4*)(zn  + (size_t)p * D + lane * 4) = oa;
  *(us4*)(zn  + (size_t)(p + B_ROWS) * D + lane * 4) = ob;
  *(us4*)(zns + (size_t)p * D + lane * 4) = sa4;
  *(us4*)(zns + (size_t)(p + B_ROWS) * D + lane * 4) = sb4;
  if (lane == 0) {
    float d = ab * ia * ib;
    pos[p] = d;
    pos[p + B_ROWS] = d;
  }
}

// ---- kernel 2: fused sim-GEMM + exp2 row-sum, 2-phase double-buffered ----
// grid = (NTOT/BM)*NSPLIT = 32*16 = 512 blocks, 512 threads (8 waves).
// Wave w owns rows [rb+32w, rb+32w+32) as two 16-row MFMA A-tiles (from zns,
// pre-scaled by 2*log2e so epilogue is raw v_exp_f32). 64-col B tiles staged
// into LDS via global_load_lds (linear dest, pre-swizzled global src,
// XOR ((row&7)<<4)); double-buffered, stage(jt+1) issued before compute(jt),
// one vmcnt(0)+barrier per jt (T3 minimum 2-phase recipe).
__global__ __launch_bounds__(512, 4) void k_gemm(const unsigned short* __restrict__ zn,
                                                 const unsigned short* __restrict__ zns,
                                                 float* __restrict__ part) {
  __shared__ char lds[2 * 32768];
  int rb = (int)(blockIdx.x / NSPLIT) * BM;
  int cs = (int)(blockIdx.x % NSPLIT);
  int cb = cs * COLS_PER_BLOCK;
  int w = threadIdx.x >> 6;
  int lane = threadIdx.x & 63;
  int hi = lane >> 4, lo = lane & 15;

  const char* znb  = (const char*)zn;
  const char* znsb = (const char*)zns;

  // A fragments (registers, scaled): lane -> row = lo, k = 32f + hi*8
  bf16x8 a0[8], a1[8];
  int r0 = rb + w * 32 + lo;
  #pragma unroll
  for (int f = 0; f < 8; f++) {
    a0[f] = *(const bf16x8*)(znsb + (size_t)r0 * 512 + f * 64 + hi * 16);
    a1[f] = *(const bf16x8*)(znsb + (size_t)(r0 + 16) * 512 + f * 64 + hi * 16);
  }

  // per-lane swizzled LDS read bases; nt*8192 + buf*32768 are additive
  // (XOR confined to bits 4..6, below both strides)
  int rdbase[8];
  #pragma unroll
  for (int f = 0; f < 8; f++)
    rdbase[f] = lo * 512 + ((f * 64 + hi * 16) ^ ((lo & 7) << 4));

  float rs[2][4] = {{0.f, 0.f, 0.f, 0.f}, {0.f, 0.f, 0.f, 0.f}};

  auto stage = [&](int bufofs, int colrow) {
    #pragma unroll
    for (int c = 0; c < 4; c++) {
      int local = w * 4096 + c * 1024 + lane * 16;         // linear tile offset
      int src = local ^ (((local >> 9) & 7) << 4);         // inverse-swizzled src
      __builtin_amdgcn_global_load_lds(
          (gch*)(znb + (size_t)colrow * 512 + src),
          (lch*)(lds + bufofs + w * 4096 + c * 1024), 16, 0, 0);
    }
  };
  auto compute = [&](int bufofs) {
    #pragma unroll
    for (int nt = 0; nt < 4; nt++) {
      f32x4 acc0 = {0.f, 0.f, 0.f, 0.f}, acc1 = {0.f, 0.f, 0.f, 0.f};
      #pragma unroll
      for (int f = 0; f < 8; f++) {
        bf16x8 b = *(const bf16x8*)(lds + rdbase[f] + bufofs + nt * 8192);
        acc0 = __builtin_amdgcn_mfma_f32_16x16x32_bf16(a0[f], b, acc0, 0, 0, 0);
        acc1 = __builtin_amdgcn_mfma_f32_16x16x32_bf16(a1[f], b, acc1, 0, 0, 0);
      }
      #pragma unroll
      for (int r = 0; r < 4; r++) {
        float e0, e1;
        asm("v_exp_f32 %0, %1" : "=v"(e0) : "v"(acc0[r]));
        asm("v_exp_f32 %0, %1" : "=v"(e1) : "v"(acc1[r]));
        rs[0][r] += e0;
        rs[1][r] += e1;
      }
    }
  };
  auto drain_barrier = []() {
    asm volatile("s_waitcnt vmcnt(0)" ::: "memory");
    __syncthreads();
  };

  stage(0, cb);                 // prologue
  drain_barrier();
  for (int jt = 0; jt < JT_COUNT; jt += 2) {
    if (jt + 1 < JT_COUNT) stage(32768, cb + (jt + 1) * 64);
    compute(0);
    drain_barrier();
    if (jt + 2 < JT_COUNT) stage(0, cb + (jt + 2) * 64);
    compute(32768);
    drain_barrier();
  }

  // reduce partial row-sums across the 16 lanes of each row-group; exclusive
  // (block,split) region in part -> plain stores, no atomics, no memset.
  #pragma unroll
  for (int m = 1; m < 16; m <<= 1) {
    #pragma unroll
    for (int t = 0; t < 2; t++)
      #pragma unroll
      for (int r = 0; r < 4; r++)
        rs[t][r] += __shfl_xor(rs[t][r], m, 64);
  }
  if (lo == 0) {
    #pragma unroll
    for (int t = 0; t < 2; t++)
      #pragma unroll
      for (int r = 0; r < 4; r++)
        part[(size_t)cs * NTOT + rb + w * 32 + t * 16 + hi * 4 + r] = rs[t][r];
  }
}

// ---- kernel 3: final loss reduction ----
__global__ __launch_bounds__(256) void k_final(const float* __restrict__ part,
                                               const float* __restrict__ pos,
                                               float* __restrict__ out) {
  int i = blockIdx.x * 256 + threadIdx.x;
  float s = 0.f;
  #pragma unroll
  for (int c = 0; c < NSPLIT; c++) s += part[(size_t)c * NTOT + i];
  float denom = s - 7.3890560989306495f;     // subtract exp(2*sim_ii), sim_ii~1
  float t = __logf(denom) - 2.0f * pos[i];
  #pragma unroll
  for (int m = 1; m < 64; m <<= 1) t += __shfl_xor(t, m, 64);
  __shared__ float wsum[4];
  int w = threadIdx.x >> 6, lane = threadIdx.x & 63;
  if (lane == 0) wsum[w] = t;
  __syncthreads();
  if (threadIdx.x == 0)
    atomicAdd(out, (wsum[0] + wsum[1] + wsum[2] + wsum[3]) * (1.0f / NTOT));
}

extern "C" void kernel_launch(void* const* d_in, const int* in_sizes, int n_in,
                              void* d_out, int out_size, void* d_ws, size_t ws_size,
                              hipStream_t stream) {
  const float* xi = (const float*)d_in[0];
  const float* xj = (const float*)d_in[1];

  unsigned short* zn  = (unsigned short*)d_ws;                       // 4 MB
  unsigned short* zns = zn + (size_t)NTOT * D;                       // 4 MB
  char* base = (char*)(zns + (size_t)NTOT * D);
  float* part = (float*)base;                                        // 512 KB
  float* pos  = (float*)(base + (size_t)NSPLIT * NTOT * 4);          // 32 KB

  k_prep<<<B_ROWS / 4, 256, 0, stream>>>(xi, xj, zn, zns, pos, (float*)d_out);
  k_gemm<<<(NTOT / BM) * NSPLIT, 512, 0, stream>>>(zn, zns, part);
  k_final<<<NTOT / 256, 256, 0, stream>>>(part, pos, (float*)d_out);
}